// Round 10
// baseline (118.154 us; speedup 1.0000x reference)
//
#include <hip/hip_runtime.h>
#include <hip/hip_bf16.h>
#include <math.h>

// Problem: VOCAB=50257, E=64, D=16, DK=32, B*S=65536, membership p=0.05
#define EDIM 64
#define DDOM 16
#define DKDIM 32
#define NTHREADS 256
#define PPB 128             // positions per block in fused kernel

// ws layout: float w1t[16][32][64] @0 | float w2t[16][64][32] (x0.1) @131072
//
// R10: single fused kernel + tiny weight-transpose pre-kernel.
//  - Block-local compaction (u8 lists in LDS) kills the prep->mlp serial
//    chain, the global lists, and the cnt memset.
//  - corr accumulates in LDS fp32 (ds atomics), out written ONCE coalesced
//    (merges R8 prep jobA's 16 MB stream with mlp output; kills ~13 MB of
//    global atomic RMW).
//  - MFMA core (layouts, gelu, u_lds repack) copied verbatim from the
//    R8/R9-verified kernels: A[m=lane&15][k=quad*8+j]; C/D col=lane&15,
//    row=quad*4+reg; B[k=quad*8+j][n=lane&15]; bf16 weights (absmax 2.4e-4).
//  - Wave w owns domains {w, w+4, w+8, w+12}: fragments loaded per domain
//    via float4 from transposed ws copies (written by prepW each call).

typedef __attribute__((ext_vector_type(8))) short bf16x8;
typedef __attribute__((ext_vector_type(4))) float f32x4;

__device__ __forceinline__ short f2bf(float f) {   // fp32 -> bf16 bits, RNE
    unsigned u = __float_as_uint(f);
    u += 0x7FFFu + ((u >> 16) & 1u);
    return (short)(u >> 16);
}

// ---------------------------------------------------------------------------
// prepW: 16 blocks — transpose weights into ws (w1t[d][ko][e]; w2t[d][e][k]*0.1)
// ---------------------------------------------------------------------------
__global__ void prepW_kernel(const float* __restrict__ W1,   // [D][E][DK]
                             const float* __restrict__ W2,   // [D][DK][E]
                             float* __restrict__ w1t,        // [D][DK][E]
                             float* __restrict__ w2t)        // [D][E][DK]
{
    const int d = blockIdx.x, thr = threadIdx.x;
    const float* __restrict__ s1 = W1 + d * (EDIM * DKDIM);
    float* __restrict__ d1 = w1t + d * (DKDIM * EDIM);
    for (int i = thr; i < EDIM * DKDIM; i += NTHREADS) {
        int e = i >> 5, k = i & 31;
        d1[k * EDIM + e] = s1[i];
    }
    const float* __restrict__ s2 = W2 + d * (DKDIM * EDIM);
    float* __restrict__ d2 = w2t + d * (DKDIM * EDIM);
    for (int i = thr; i < DKDIM * EDIM; i += NTHREADS) {
        int k = i >> 6, e = i & 63;
        d2[e * DKDIM + k] = 0.1f * s2[i];
    }
}

// ---------------------------------------------------------------------------
// fused: grid = ceil(ntok/128), 256 threads (4 waves), ~2 blocks/CU.
// ---------------------------------------------------------------------------
__global__ __launch_bounds__(256, 2) void fused_kernel(
    const int* __restrict__ x,
    const float* __restrict__ tab,
    const float* __restrict__ w1t,  // [D][32 ko][64 e]
    const float* __restrict__ w2t,  // [D][64 e][32 k] (x0.1)
    const unsigned char* __restrict__ memb,
    float* __restrict__ out,
    int ntok)
{
    __shared__ float corr[PPB][68];          // 34.8 KB, stride 68 (16B-aligned)
    __shared__ float u_lds[4][16][36];       // per-wave repack, 9.2 KB
    __shared__ int   tok_lds[PPB];
    __shared__ unsigned char dlist[DDOM][PPB];
    __shared__ int   dcnt[DDOM];
    __shared__ int   det_wave[4];

    const int thr = threadIdx.x, lane = thr & 63, wid = thr >> 6;
    const int p0 = blockIdx.x * PPB;

    // ---- dtype detect (scan first 4096 B; membership >= 804112 B min) ----
    {
        const uint4 v = ((const uint4*)memb)[thr];
        unsigned int w[4] = {v.x, v.y, v.z, v.w};
        bool sawbf = false, saw8 = false;
        #pragma unroll
        for (int dw = 0; dw < 4; ++dw)
            #pragma unroll
            for (int b = 0; b < 4; ++b) {
                unsigned int byte = (w[dw] >> (8 * b)) & 0xFFu;
                if (byte > 1u) sawbf = true;
                if (byte == 1u && b != 0) saw8 = true;
            }
        unsigned long long b1 = __ballot(sawbf), b2 = __ballot(saw8);
        if (lane == 0) det_wave[wid] = (b1 ? 1 : 0) | (b2 ? 2 : 0);
    }
    // ---- init: corr zero, counters, token ids ----
    if (thr < DDOM) dcnt[thr] = 0;
    #pragma unroll
    for (int i = thr; i < PPB * 68; i += NTHREADS) ((float*)corr)[i] = 0.f;
    if (thr < PPB) {
        int t = p0 + thr;
        tok_lds[thr] = (t < ntok) ? x[t] : 0;
    }
    __syncthreads();
    const int mcode = det_wave[0] | det_wave[1] | det_wave[2] | det_wave[3];

    // ---- masks + local compaction ----
    if (thr < PPB && p0 + thr < ntok) {
        const int tok = tok_lds[thr];
        unsigned int m = 0;
        if (mcode & 1) {          // bf16 0.0/1.0
            const unsigned short* p = (const unsigned short*)memb + (size_t)tok * DDOM;
            #pragma unroll
            for (int d = 0; d < DDOM; ++d) m |= (unsigned)(p[d] != 0) << d;
        } else if (mcode & 2) {   // uint8
            const unsigned char* p = memb + (size_t)tok * DDOM;
            #pragma unroll
            for (int d = 0; d < DDOM; ++d) m |= (unsigned)(p[d] != 0) << d;
        } else {                  // int32
            const int* p = (const int*)memb + (size_t)tok * DDOM;
            #pragma unroll
            for (int d = 0; d < DDOM; ++d) m |= (unsigned)(p[d] != 0) << d;
        }
        #pragma unroll
        for (int d = 0; d < DDOM; ++d)
            if ((m >> d) & 1u) {
                int idx = atomicAdd(&dcnt[d], 1);
                dlist[d][idx] = (unsigned char)thr;
            }
    }
    __syncthreads();

    // ---- MFMA phase: wave wid handles domains wid, wid+4, wid+8, wid+12 ----
    const int col  = lane & 15;
    const int quad = lane >> 4;
    #pragma unroll 1
    for (int dd = 0; dd < 4; ++dd) {
        const int d = wid + dd * 4;
        const int cntd = dcnt[d];
        if (cntd == 0) continue;

        // weight fragments for this domain (float4 from transposed copies)
        const float* __restrict__ w1d = w1t + d * (DKDIM * EDIM);
        const float* __restrict__ w2d = w2t + d * (DKDIM * EDIM);
        bf16x8 w1f[2][2];   // [K-tile tk][n-half tn]: B[k=e][n=ko]
        #pragma unroll
        for (int tk = 0; tk < 2; ++tk)
            #pragma unroll
            for (int tn = 0; tn < 2; ++tn) {
                const float* p = w1d + (tn * 16 + col) * EDIM + tk * 32 + quad * 8;
                f32x4 a = *(const f32x4*)(p);
                f32x4 b = *(const f32x4*)(p + 4);
                w1f[tk][tn][0] = f2bf(a.x); w1f[tk][tn][1] = f2bf(a.y);
                w1f[tk][tn][2] = f2bf(a.z); w1f[tk][tn][3] = f2bf(a.w);
                w1f[tk][tn][4] = f2bf(b.x); w1f[tk][tn][5] = f2bf(b.y);
                w1f[tk][tn][6] = f2bf(b.z); w1f[tk][tn][7] = f2bf(b.w);
            }
        bf16x8 w2f[4];      // [e-tile te]: B[k][n=e], pre-scaled by 0.1
        #pragma unroll
        for (int te = 0; te < 4; ++te) {
            const float* p = w2d + (te * 16 + col) * DKDIM + quad * 8;
            f32x4 a = *(const f32x4*)(p);
            f32x4 b = *(const f32x4*)(p + 4);
            w2f[te][0] = f2bf(a.x); w2f[te][1] = f2bf(a.y);
            w2f[te][2] = f2bf(a.z); w2f[te][3] = f2bf(a.w);
            w2f[te][4] = f2bf(b.x); w2f[te][5] = f2bf(b.y);
            w2f[te][6] = f2bf(b.z); w2f[te][7] = f2bf(b.w);
        }

        const int ngrp = (cntd + 15) >> 4;
        for (int g = 0; g < ngrp; ++g) {
            const int base = g * 16;
            const int ti = base + col;
            const bool v = ti < cntd;
            const int loc = v ? (int)dlist[d][ti] : 0;
            const int tok = tok_lds[loc];

            // A-fragments of h: A[m=col][k=e=tk*32+quad*8+j]
            const float* __restrict__ hrow = tab + (size_t)tok * EDIM;
            bf16x8 ha[2];
            #pragma unroll
            for (int tk = 0; tk < 2; ++tk) {
                f32x4 a = *(const f32x4*)(hrow + tk * 32 + quad * 8);
                f32x4 b = *(const f32x4*)(hrow + tk * 32 + quad * 8 + 4);
                ha[tk][0] = f2bf(a.x); ha[tk][1] = f2bf(a.y);
                ha[tk][2] = f2bf(a.z); ha[tk][3] = f2bf(a.w);
                ha[tk][4] = f2bf(b.x); ha[tk][5] = f2bf(b.y);
                ha[tk][6] = f2bf(b.z); ha[tk][7] = f2bf(b.w);
            }

            // step1: U[16 x 32]
            #pragma unroll
            for (int tn = 0; tn < 2; ++tn) {
                f32x4 acc = {0.f, 0.f, 0.f, 0.f};
                acc = __builtin_amdgcn_mfma_f32_16x16x32_bf16(ha[0], w1f[0][tn], acc, 0, 0, 0);
                acc = __builtin_amdgcn_mfma_f32_16x16x32_bf16(ha[1], w1f[1][tn], acc, 0, 0, 0);
                #pragma unroll
                for (int r = 0; r < 4; ++r) {
                    float u = acc[r];
                    float gg, au = fabsf(u);
                    if (__builtin_expect(au > 0.35f, 0)) {
                        gg = 0.5f * u * (1.f + erff(u * 0.70710678118654752f));
                    } else {
                        float uu = u * u;
                        gg = u * (0.5f + u * (0.3989422804f + uu * (-0.06649038f + uu * 0.00997356f)));
                    }
                    u_lds[wid][quad * 4 + r][tn * 16 + col] = gg;
                }
            }

            // repack U: D-layout -> A-layout (same-wave RAW, in-order DS pipe)
            bf16x8 ua;
            {
                const float* __restrict__ up = &u_lds[wid][col][quad * 8];
                f32x4 a = *(const f32x4*)(up);
                f32x4 b = *(const f32x4*)(up + 4);
                ua[0] = f2bf(a.x); ua[1] = f2bf(a.y); ua[2] = f2bf(a.z); ua[3] = f2bf(a.w);
                ua[4] = f2bf(b.x); ua[5] = f2bf(b.y); ua[6] = f2bf(b.z); ua[7] = f2bf(b.w);
            }

            // step2: C = U x (0.1*W2); accumulate into LDS corr
            #pragma unroll
            for (int te = 0; te < 4; ++te) {
                f32x4 acc = {0.f, 0.f, 0.f, 0.f};
                acc = __builtin_amdgcn_mfma_f32_16x16x32_bf16(ua, w2f[te], acc, 0, 0, 0);
                #pragma unroll
                for (int r = 0; r < 4; ++r) {
                    const int m = quad * 4 + r;
                    const int locm = __shfl(loc, m, 64);   // loc of token row m
                    if (base + m < cntd) {
                        atomicAdd(&corr[locm][te * 16 + col], acc[r]);
                    }
                }
            }
        }
    }
    __syncthreads();

    // ---- epilogue: out = h + corr (coalesced float4) ----
    for (int i = thr; i < PPB * 16; i += NTHREADS) {
        const int l = i >> 4, s = i & 15;
        if (p0 + l < ntok) {
            float4 hv = ((const float4*)(tab + (size_t)tok_lds[l] * EDIM))[s];
            float4 cv = *(const float4*)&corr[l][s * 4];
            float4 o = {hv.x + cv.x, hv.y + cv.y, hv.z + cv.z, hv.w + cv.w};
            ((float4*)(out + (size_t)(p0 + l) * EDIM))[s] = o;
        }
    }
}

// ---------------------------------------------------------------------------
// Fallback (ws too small for weight transposes): round-2 kernel, known-correct.
// ---------------------------------------------------------------------------
__global__ __launch_bounds__(256, 4) void domain_embed_fused(
    const int* __restrict__ x, const float* __restrict__ tab,
    const float* __restrict__ W1, const float* __restrict__ W2,
    const unsigned char* __restrict__ memb, float* __restrict__ out, int ntok)
{
    __shared__ float h_lds[32][EDIM];
    __shared__ float corr[32][EDIM];
    __shared__ int   tok_lds[32];
    __shared__ unsigned int mask_lds[32];
    __shared__ unsigned short pairs[32 * DDOM];
    __shared__ int npairs;
    __shared__ int det_wave[4];
    const int thr = threadIdx.x, lane = thr & 63, wid = thr >> 6;
    const int tok0 = blockIdx.x * 32;
    if (thr < 32) { int t = tok0 + thr; tok_lds[thr] = (t < ntok) ? x[t] : 0; }
    #pragma unroll
    for (int i = 0; i < 8; ++i) ((float*)corr)[thr + i * 256] = 0.f;
    if (thr == 0) npairs = 0;
    {
        const uint4 v = ((const uint4*)memb)[thr];
        unsigned int w[4] = {v.x, v.y, v.z, v.w};
        bool sawbf = false, saw8 = false;
        #pragma unroll
        for (int dw = 0; dw < 4; ++dw)
            #pragma unroll
            for (int b = 0; b < 4; ++b) {
                unsigned int byte = (w[dw] >> (8 * b)) & 0xFFu;
                if (byte > 1u) sawbf = true;
                if (byte == 1u && b != 0) saw8 = true;
            }
        unsigned long long b1 = __ballot(sawbf), b2 = __ballot(saw8);
        if (lane == 0) det_wave[wid] = (b1 ? 1 : 0) | (b2 ? 2 : 0);
    }
    __syncthreads();
    const int mcode = det_wave[0] | det_wave[1] | det_wave[2] | det_wave[3];
    #pragma unroll
    for (int pass = 0; pass < 2; ++pass) {
        int row = pass * 16 + (thr >> 4);
        const float4 hv = ((const float4*)(tab + (size_t)tok_lds[row] * EDIM))[thr & 15];
        ((float4*)&h_lds[row][0])[thr & 15] = hv;
    }
    if (thr < 32) {
        int tokid = tok_lds[thr];
        unsigned int m = 0;
        if (mcode & 1) { const unsigned short* p = (const unsigned short*)memb + (size_t)tokid * DDOM;
            #pragma unroll
            for (int d = 0; d < DDOM; ++d) m |= (unsigned)(p[d] != 0) << d;
        } else if (mcode & 2) { const unsigned char* p = memb + (size_t)tokid * DDOM;
            #pragma unroll
            for (int d = 0; d < DDOM; ++d) m |= (unsigned)(p[d] != 0) << d;
        } else { const int* p = (const int*)memb + (size_t)tokid * DDOM;
            #pragma unroll
            for (int d = 0; d < DDOM; ++d) m |= (unsigned)(p[d] != 0) << d;
        }
        mask_lds[thr] = m;
    }
    __syncthreads();
    for (int cc = thr; cc < 32 * DDOM; cc += 256) {
        int t = cc >> 4, d = cc & 15;
        if ((mask_lds[t] >> d) & 1u) { int idx = atomicAdd(&npairs, 1); pairs[idx] = (unsigned short)cc; }
    }
    __syncthreads();
    const int np = npairs, k = lane & 31, p = lane >> 5;
    for (int pi = wid; pi < np; pi += 4) {
        int cc = pairs[pi], t = cc >> 4, d = cc & 15;
        const float* __restrict__ w1 = W1 + d * (EDIM * DKDIM);
        float u = 0.f;
        #pragma unroll
        for (int j4 = 0; j4 < 8; ++j4) {
            float4 hv = ((const float4*)&h_lds[t][p * 32])[j4];
            int e = p * 32 + j4 * 4;
            u = fmaf(hv.x, w1[(e + 0) * DKDIM + k], u);
            u = fmaf(hv.y, w1[(e + 1) * DKDIM + k], u);
            u = fmaf(hv.z, w1[(e + 2) * DKDIM + k], u);
            u = fmaf(hv.w, w1[(e + 3) * DKDIM + k], u);
        }
        u += __shfl_xor(u, 32, 64);
        float gg, au = fabsf(u);
        if (__builtin_expect(__ballot(au > 0.35f) != 0ull, 0))
            gg = 0.5f * u * (1.f + erff(u * 0.70710678118654752f));
        else { float uu = u * u; gg = u * (0.5f + u * (0.3989422804f + uu * (-0.06649038f + uu * 0.00997356f))); }
        const float* __restrict__ w2 = W2 + d * (DKDIM * EDIM);
        float cp = 0.f;
        #pragma unroll
        for (int kk = 0; kk < DKDIM; ++kk) cp = fmaf(__shfl(gg, kk, 64), w2[kk * EDIM + lane], cp);
        atomicAdd(&corr[t][lane], cp);
    }
    __syncthreads();
    #pragma unroll
    for (int pass = 0; pass < 2; ++pass) {
        int row = pass * 16 + (thr >> 4), gt = tok0 + row;
        if (gt < ntok) {
            float4 hv = ((const float4*)&h_lds[row][0])[thr & 15];
            float4 cv = ((const float4*)&corr[row][0])[thr & 15];
            float4 o = {hv.x + 0.1f * cv.x, hv.y + 0.1f * cv.y, hv.z + 0.1f * cv.z, hv.w + 0.1f * cv.w};
            ((float4*)(out + (size_t)gt * EDIM))[thr & 15] = o;
        }
    }
}

extern "C" void kernel_launch(void* const* d_in, const int* in_sizes, int n_in,
                              void* d_out, int out_size, void* d_ws, size_t ws_size,
                              hipStream_t stream) {
    const int*   x    = (const int*)  d_in[0];
    const float* tab  = (const float*)d_in[1];
    const float* W1   = (const float*)d_in[2];
    const float* W2   = (const float*)d_in[3];
    const unsigned char* memb = (const unsigned char*)d_in[4];
    float* out = (float*)d_out;
    const int ntok = in_sizes[0];

    const size_t wbytes = (size_t)DDOM * DKDIM * EDIM * sizeof(float);   // 128 KB each
    if (ws_size >= 2 * wbytes) {
        float* w1t = (float*)d_ws;
        float* w2t = (float*)((char*)d_ws + wbytes);
        prepW_kernel<<<DDOM, NTHREADS, 0, stream>>>(W1, W2, w1t, w2t);
        const int nblk = (ntok + PPB - 1) / PPB;
        fused_kernel<<<nblk, NTHREADS, 0, stream>>>(x, tab, w1t, w2t, memb, out, ntok);
    } else {
        const int blocks = (ntok + 31) / 32;
        domain_embed_fused<<<blocks, NTHREADS, 0, stream>>>(x, tab, W1, W2, memb, out, ntok);
    }
}

// Round 11
// 104.802 us; speedup vs baseline: 1.1274x; 1.1274x over previous
//
#include <hip/hip_runtime.h>
#include <hip/hip_bf16.h>
#include <math.h>

// Problem: VOCAB=50257, E=64, D=16, DK=32, B*S=65536, membership p=0.05
#define EDIM 64
#define DDOM 16
#define DKDIM 32
#define NTHREADS 256
#define NBA 1024            // job-A blocks in prep (out = h streaming)
#define MBD 32              // blocks per domain in mlp (R8 value — R9's 48 regressed)
#define CNT_STRIDE 32       // ints between cnt[d] atomic targets (128 B)

// ws layout: int cnt[16*32] @0 (2048 B) | float w1t[16][32][64] @2048 |
//            float w2t[16][64][32] (x0.1) @133120 | u32 lists[16][ntok] @264192
// lists entries packed: (tokid<<16)|pos  (both < 2^16).
//
// R11 = R8 structure exactly (MBD=32, launch_bounds(256,2), 1.6 groups/wave)
// + R9's two mechanical improvements, isolated:
//  - frag loads are float4 from ws-transposed copies (16 b128 vs 96 dwords)
//  - lists pack tokid|pos (2-hop gather chain, was 3)
// R10 lesson: block-local compaction starves tiles (40% full) and repays
// fragment loads per domain per block — global domain-major compaction stays.

typedef __attribute__((ext_vector_type(8))) short bf16x8;
typedef __attribute__((ext_vector_type(4))) float f32x4;

__device__ __forceinline__ short f2bf(float f) {   // fp32 -> bf16 bits, RNE
    unsigned u = __float_as_uint(f);
    u += 0x7FFFu + ((u >> 16) & 1u);
    return (short)(u >> 16);
}

// ---------------------------------------------------------------------------
__global__ void prep_kernel(const int* __restrict__ x,
                            const float* __restrict__ tab,
                            const float* __restrict__ W1,   // [D][E][DK]
                            const float* __restrict__ W2,   // [D][DK][E]
                            const unsigned char* __restrict__ memb,
                            float* __restrict__ out,
                            int* __restrict__ cnt,          // [16*CNT_STRIDE]
                            float* __restrict__ w1t,        // [16][32][64]
                            float* __restrict__ w2t,        // [16][64][32]
                            unsigned int* __restrict__ lists,
                            int ntok, int nbb)
{
    const int thr = threadIdx.x;
    const int bid = blockIdx.x;
    if (bid < NBA) {
        // ---- job A: out = embed_table[x]  (coalesced float4 gather-stream)
        const int nf4 = ntok * 16;
        for (int i = bid * NTHREADS + thr; i < nf4; i += NBA * NTHREADS) {
            int t = i >> 4, s = i & 15;
            int tok = x[t];
            float4 hv = ((const float4*)(tab + (size_t)tok * EDIM))[s];
            ((float4*)(out + (size_t)t * EDIM))[s] = hv;
        }
        return;
    }
    if (bid >= NBA + nbb) {
        // ---- job C: weight transposes (one block per domain)
        const int d = bid - NBA - nbb;
        const float* __restrict__ s1 = W1 + d * (EDIM * DKDIM);   // [e][k]
        float* __restrict__ d1 = w1t + d * (DKDIM * EDIM);        // [k][e]
        for (int i = thr; i < EDIM * DKDIM; i += NTHREADS) {
            int e = i >> 5, k = i & 31;
            d1[k * EDIM + e] = s1[i];
        }
        const float* __restrict__ s2 = W2 + d * (DKDIM * EDIM);   // [k][e]
        float* __restrict__ d2 = w2t + d * (DKDIM * EDIM);        // [e][k]
        for (int i = thr; i < DKDIM * EDIM; i += NTHREADS) {
            int k = i >> 6, e = i & 63;
            d2[e * DKDIM + k] = 0.1f * s2[i];                     // fold 0.1 here
        }
        return;
    }
    // ---- job B: membership dtype detect + per-domain compaction
    __shared__ int det;
    __shared__ int lcnt[DDOM], lbase[DDOM], lpos[DDOM];
    if (thr == 0) det = 0;
    if (thr < DDOM) lcnt[thr] = 0;
    __syncthreads();
    {   // scan first 4096 bytes (membership >= 804112 elements >= 1 B: in-bounds)
        const uint4 v = ((const uint4*)memb)[thr];
        unsigned int w[4] = {v.x, v.y, v.z, v.w};
        int saw = 0;
        #pragma unroll
        for (int dw = 0; dw < 4; ++dw)
            #pragma unroll
            for (int b = 0; b < 4; ++b) {
                unsigned int byte = (w[dw] >> (8 * b)) & 0xFFu;
                if (byte > 1u) saw |= 1;            // bf16 signature bytes
                if (byte == 1u && b != 0) saw |= 2; // '1' at offset %4 != 0 -> u8
            }
        if (saw) atomicOr(&det, saw);
    }
    __syncthreads();
    const int mcode = det;

    const int t = (bid - NBA) * NTHREADS + thr;
    unsigned int m = 0;
    int tok = 0;
    if (t < ntok) {
        tok = x[t];
        if (mcode & 1) {          // bf16 0.0/1.0
            const unsigned short* p = (const unsigned short*)memb + (size_t)tok * DDOM;
            #pragma unroll
            for (int d = 0; d < DDOM; ++d) m |= (unsigned)(p[d] != 0) << d;
        } else if (mcode & 2) {   // uint8
            const unsigned char* p = memb + (size_t)tok * DDOM;
            #pragma unroll
            for (int d = 0; d < DDOM; ++d) m |= (unsigned)(p[d] != 0) << d;
        } else {                  // int32
            const int* p = (const int*)memb + (size_t)tok * DDOM;
            #pragma unroll
            for (int d = 0; d < DDOM; ++d) m |= (unsigned)(p[d] != 0) << d;
        }
    }
    #pragma unroll
    for (int d = 0; d < DDOM; ++d)
        if ((m >> d) & 1u) atomicAdd(&lcnt[d], 1);
    __syncthreads();
    if (thr < DDOM) {
        lbase[thr] = atomicAdd(&cnt[thr * CNT_STRIDE], lcnt[thr]);  // padded target
        lpos[thr] = 0;
    }
    __syncthreads();
    const unsigned int packed = ((unsigned)tok << 16) | (unsigned)(t & 0xFFFF);
    #pragma unroll
    for (int d = 0; d < DDOM; ++d)
        if ((m >> d) & 1u) {
            int p = atomicAdd(&lpos[d], 1);
            lists[(size_t)d * ntok + lbase[d] + p] = packed;
        }
}

// ---------------------------------------------------------------------------
// mlp7: grid = 16 domains x 32 blocks, 256 threads (4 waves), 2 blocks/CU.
// R8 shape; weights in bf16 MFMA fragments loaded once per wave via float4.
// ---------------------------------------------------------------------------
__global__ __launch_bounds__(256, 2) void mlp7_kernel(
    const unsigned int* __restrict__ lists,
    const int* __restrict__ cnt,
    const float* __restrict__ tab,
    const float* __restrict__ w1t,  // [D][32 ko][64 e]
    const float* __restrict__ w2t,  // [D][64 e][32 k]  (x0.1)
    float* __restrict__ out,
    int ntok)
{
    __shared__ float u_lds[4][16][36];   // per-wave U repack, padded  9.2 KB

    const int thr = threadIdx.x, lane = thr & 63, wid = thr >> 6;
    const int d    = blockIdx.x >> 5;    // MBD = 32
    const int blk  = blockIdx.x & (MBD - 1);
    const int n    = cnt[d * CNT_STRIDE];
    if (n == 0) return;

    const int col  = lane & 15;   // n-index inside a 16-wide tile
    const int quad = lane >> 4;   // k-index base = quad*8

    // ---- weight fragments, once per wave (float4 loads, transposed src) ----
    const float* __restrict__ w1d = w1t + d * (DKDIM * EDIM);
    const float* __restrict__ w2d = w2t + d * (DKDIM * EDIM);
    bf16x8 w1f[2][2];   // [K-tile tk][n-half tn]: B[k=e][n=ko]
    #pragma unroll
    for (int tk = 0; tk < 2; ++tk)
        #pragma unroll
        for (int tn = 0; tn < 2; ++tn) {
            const float* p = w1d + (tn * 16 + col) * EDIM + tk * 32 + quad * 8;
            f32x4 a = *(const f32x4*)(p);
            f32x4 b = *(const f32x4*)(p + 4);
            w1f[tk][tn][0] = f2bf(a.x); w1f[tk][tn][1] = f2bf(a.y);
            w1f[tk][tn][2] = f2bf(a.z); w1f[tk][tn][3] = f2bf(a.w);
            w1f[tk][tn][4] = f2bf(b.x); w1f[tk][tn][5] = f2bf(b.y);
            w1f[tk][tn][6] = f2bf(b.z); w1f[tk][tn][7] = f2bf(b.w);
        }
    bf16x8 w2f[4];      // [e-tile te]: B[k][n=e], pre-scaled by 0.1
    #pragma unroll
    for (int te = 0; te < 4; ++te) {
        const float* p = w2d + (te * 16 + col) * DKDIM + quad * 8;
        f32x4 a = *(const f32x4*)(p);
        f32x4 b = *(const f32x4*)(p + 4);
        w2f[te][0] = f2bf(a.x); w2f[te][1] = f2bf(a.y);
        w2f[te][2] = f2bf(a.z); w2f[te][3] = f2bf(a.w);
        w2f[te][4] = f2bf(b.x); w2f[te][5] = f2bf(b.y);
        w2f[te][6] = f2bf(b.z); w2f[te][7] = f2bf(b.w);
    }

    const int ngrp = (n + 15) >> 4;
    for (int g = blk * 4 + wid; g < ngrp; g += MBD * 4) {
        const int base = g * 16;
        const int ti = base + col;                   // lane carries token row m=col
        const bool v = ti < n;
        const unsigned int lst = v ? lists[(size_t)d * ntok + ti] : 0u;
        const int pos   = (int)(lst & 0xFFFFu);
        const int tokid = (int)(lst >> 16);

        // A-fragments of h: A[m=col][k=e=tk*32+quad*8+j]
        const float* __restrict__ hrow = tab + (size_t)tokid * EDIM;
        bf16x8 ha[2];
        #pragma unroll
        for (int tk = 0; tk < 2; ++tk) {
            f32x4 a = *(const f32x4*)(hrow + tk * 32 + quad * 8);
            f32x4 b = *(const f32x4*)(hrow + tk * 32 + quad * 8 + 4);
            ha[tk][0] = f2bf(a.x); ha[tk][1] = f2bf(a.y);
            ha[tk][2] = f2bf(a.z); ha[tk][3] = f2bf(a.w);
            ha[tk][4] = f2bf(b.x); ha[tk][5] = f2bf(b.y);
            ha[tk][6] = f2bf(b.z); ha[tk][7] = f2bf(b.w);
        }

        // ---- step1: U[16 tok x 32 ko] ----
        #pragma unroll
        for (int tn = 0; tn < 2; ++tn) {
            f32x4 acc = {0.f, 0.f, 0.f, 0.f};
            acc = __builtin_amdgcn_mfma_f32_16x16x32_bf16(ha[0], w1f[0][tn], acc, 0, 0, 0);
            acc = __builtin_amdgcn_mfma_f32_16x16x32_bf16(ha[1], w1f[1][tn], acc, 0, 0, 0);
            // gelu on D-frag (D[m=quad*4+r][ko=tn*16+col]) -> u_lds[m][ko]
            #pragma unroll
            for (int r = 0; r < 4; ++r) {
                float u = acc[r];
                float gg, au = fabsf(u);
                if (__builtin_expect(au > 0.35f, 0)) {
                    gg = 0.5f * u * (1.f + erff(u * 0.70710678118654752f));
                } else {
                    float uu = u * u;
                    gg = u * (0.5f + u * (0.3989422804f + uu * (-0.06649038f + uu * 0.00997356f)));
                }
                u_lds[wid][quad * 4 + r][tn * 16 + col] = gg;
            }
        }

        // ---- repack U: D-layout -> A-layout (same-wave RAW, in-order DS) ----
        bf16x8 ua;
        {
            const float* __restrict__ up = &u_lds[wid][col][quad * 8];
            f32x4 a = *(const f32x4*)(up);
            f32x4 b = *(const f32x4*)(up + 4);
            ua[0] = f2bf(a.x); ua[1] = f2bf(a.y); ua[2] = f2bf(a.z); ua[3] = f2bf(a.w);
            ua[4] = f2bf(b.x); ua[5] = f2bf(b.y); ua[6] = f2bf(b.z); ua[7] = f2bf(b.w);
        }

        // ---- step2: C = U x (0.1*W2); atomicAdd into out ----
        #pragma unroll
        for (int te = 0; te < 4; ++te) {
            f32x4 acc = {0.f, 0.f, 0.f, 0.f};
            acc = __builtin_amdgcn_mfma_f32_16x16x32_bf16(ua, w2f[te], acc, 0, 0, 0);
            #pragma unroll
            for (int r = 0; r < 4; ++r) {
                int m  = quad * 4 + r;
                int pm = __shfl(pos, m, 64);      // pos of token row m
                if (base + m < n) {
                    atomicAdd(&out[(size_t)pm * EDIM + te * 16 + col], acc[r]);
                }
            }
        }
    }
}

// ---------------------------------------------------------------------------
// Fallback (ws too small or ntok > 65536): round-2 fused kernel, known-correct.
// ---------------------------------------------------------------------------
__global__ __launch_bounds__(256, 4) void domain_embed_fused(
    const int* __restrict__ x, const float* __restrict__ tab,
    const float* __restrict__ W1, const float* __restrict__ W2,
    const unsigned char* __restrict__ memb, float* __restrict__ out, int ntok)
{
    __shared__ float h_lds[32][EDIM];
    __shared__ float corr[32][EDIM];
    __shared__ int   tok_lds[32];
    __shared__ unsigned int mask_lds[32];
    __shared__ unsigned short pairs[32 * DDOM];
    __shared__ int npairs;
    __shared__ int det_wave[4];
    const int thr = threadIdx.x, lane = thr & 63, wid = thr >> 6;
    const int tok0 = blockIdx.x * 32;
    if (thr < 32) { int t = tok0 + thr; tok_lds[thr] = (t < ntok) ? x[t] : 0; }
    #pragma unroll
    for (int i = 0; i < 8; ++i) ((float*)corr)[thr + i * 256] = 0.f;
    if (thr == 0) npairs = 0;
    {
        const uint4 v = ((const uint4*)memb)[thr];
        unsigned int w[4] = {v.x, v.y, v.z, v.w};
        bool sawbf = false, saw8 = false;
        #pragma unroll
        for (int dw = 0; dw < 4; ++dw)
            #pragma unroll
            for (int b = 0; b < 4; ++b) {
                unsigned int byte = (w[dw] >> (8 * b)) & 0xFFu;
                if (byte > 1u) sawbf = true;
                if (byte == 1u && b != 0) saw8 = true;
            }
        unsigned long long b1 = __ballot(sawbf), b2 = __ballot(saw8);
        if (lane == 0) det_wave[wid] = (b1 ? 1 : 0) | (b2 ? 2 : 0);
    }
    __syncthreads();
    const int mcode = det_wave[0] | det_wave[1] | det_wave[2] | det_wave[3];
    #pragma unroll
    for (int pass = 0; pass < 2; ++pass) {
        int row = pass * 16 + (thr >> 4);
        const float4 hv = ((const float4*)(tab + (size_t)tok_lds[row] * EDIM))[thr & 15];
        ((float4*)&h_lds[row][0])[thr & 15] = hv;
    }
    if (thr < 32) {
        int tokid = tok_lds[thr];
        unsigned int m = 0;
        if (mcode & 1) { const unsigned short* p = (const unsigned short*)memb + (size_t)tokid * DDOM;
            #pragma unroll
            for (int d = 0; d < DDOM; ++d) m |= (unsigned)(p[d] != 0) << d;
        } else if (mcode & 2) { const unsigned char* p = memb + (size_t)tokid * DDOM;
            #pragma unroll
            for (int d = 0; d < DDOM; ++d) m |= (unsigned)(p[d] != 0) << d;
        } else { const int* p = (const int*)memb + (size_t)tokid * DDOM;
            #pragma unroll
            for (int d = 0; d < DDOM; ++d) m |= (unsigned)(p[d] != 0) << d;
        }
        mask_lds[thr] = m;
    }
    __syncthreads();
    for (int cc = thr; cc < 32 * DDOM; cc += 256) {
        int t = cc >> 4, d = cc & 15;
        if ((mask_lds[t] >> d) & 1u) { int idx = atomicAdd(&npairs, 1); pairs[idx] = (unsigned short)cc; }
    }
    __syncthreads();
    const int np = npairs, k = lane & 31, p = lane >> 5;
    for (int pi = wid; pi < np; pi += 4) {
        int cc = pairs[pi], t = cc >> 4, d = cc & 15;
        const float* __restrict__ w1 = W1 + d * (EDIM * DKDIM);
        float u = 0.f;
        #pragma unroll
        for (int j4 = 0; j4 < 8; ++j4) {
            float4 hv = ((const float4*)&h_lds[t][p * 32])[j4];
            int e = p * 32 + j4 * 4;
            u = fmaf(hv.x, w1[(e + 0) * DKDIM + k], u);
            u = fmaf(hv.y, w1[(e + 1) * DKDIM + k], u);
            u = fmaf(hv.z, w1[(e + 2) * DKDIM + k], u);
            u = fmaf(hv.w, w1[(e + 3) * DKDIM + k], u);
        }
        u += __shfl_xor(u, 32, 64);
        float gg, au = fabsf(u);
        if (__builtin_expect(__ballot(au > 0.35f) != 0ull, 0))
            gg = 0.5f * u * (1.f + erff(u * 0.70710678118654752f));
        else { float uu = u * u; gg = u * (0.5f + u * (0.3989422804f + uu * (-0.06649038f + uu * 0.00997356f))); }
        const float* __restrict__ w2 = W2 + d * (DKDIM * EDIM);
        float cp = 0.f;
        #pragma unroll
        for (int kk = 0; kk < DKDIM; ++kk) cp = fmaf(__shfl(gg, kk, 64), w2[kk * EDIM + lane], cp);
        atomicAdd(&corr[t][lane], cp);
    }
    __syncthreads();
    #pragma unroll
    for (int pass = 0; pass < 2; ++pass) {
        int row = pass * 16 + (thr >> 4), gt = tok0 + row;
        if (gt < ntok) {
            float4 hv = ((const float4*)&h_lds[row][0])[thr & 15];
            float4 cv = ((const float4*)&corr[row][0])[thr & 15];
            float4 o = {hv.x + 0.1f * cv.x, hv.y + 0.1f * cv.y, hv.z + 0.1f * cv.z, hv.w + 0.1f * cv.w};
            ((float4*)(out + (size_t)gt * EDIM))[thr & 15] = o;
        }
    }
}

extern "C" void kernel_launch(void* const* d_in, const int* in_sizes, int n_in,
                              void* d_out, int out_size, void* d_ws, size_t ws_size,
                              hipStream_t stream) {
    const int*   x    = (const int*)  d_in[0];
    const float* tab  = (const float*)d_in[1];
    const float* W1   = (const float*)d_in[2];
    const float* W2   = (const float*)d_in[3];
    const unsigned char* memb = (const unsigned char*)d_in[4];
    float* out = (float*)d_out;
    const int ntok = in_sizes[0];

    const size_t cnt_bytes = (size_t)DDOM * CNT_STRIDE * sizeof(int);     // 2048
    const size_t w1t_off   = cnt_bytes;
    const size_t w2t_off   = w1t_off + (size_t)DDOM * DKDIM * EDIM * sizeof(float);
    const size_t lists_off = w2t_off + (size_t)DDOM * DKDIM * EDIM * sizeof(float);
    const size_t need      = lists_off + (size_t)DDOM * (size_t)ntok * sizeof(int);
    if (ws_size >= need && ntok <= 65536) {
        int*   cnt   = (int*)d_ws;
        float* w1t   = (float*)((char*)d_ws + w1t_off);
        float* w2t   = (float*)((char*)d_ws + w2t_off);
        unsigned int* lists = (unsigned int*)((char*)d_ws + lists_off);
        hipMemsetAsync(d_ws, 0, cnt_bytes, stream);        // zero cnt (ws poisoned)
        const int nbb = (ntok + NTHREADS - 1) / NTHREADS;
        prep_kernel<<<NBA + nbb + DDOM, NTHREADS, 0, stream>>>(
            x, tab, W1, W2, memb, out, cnt, w1t, w2t, lists, ntok, nbb);
        mlp7_kernel<<<DDOM * MBD, NTHREADS, 0, stream>>>(
            lists, cnt, tab, w1t, w2t, out, ntok);
    } else {
        const int blocks = (ntok + 31) / 32;
        domain_embed_fused<<<blocks, NTHREADS, 0, stream>>>(x, tab, W1, W2, memb, out, ntok);
    }
}

// Round 12
// 100.956 us; speedup vs baseline: 1.1704x; 1.0381x over previous
//
#include <hip/hip_runtime.h>
#include <hip/hip_bf16.h>
#include <math.h>

// Problem: VOCAB=50257, E=64, D=16, DK=32, B*S=65536, membership p=0.05
#define EDIM 64
#define DDOM 16
#define DKDIM 32
#define NTHREADS 256
#define NBA 1024            // job-A blocks in prep (out = h streaming)
#define MBD 32              // blocks per domain in mlp5
#define CNT_STRIDE 32       // ints between cnt[d] atomic targets (128 B)

// ws layout: int cnt[16*CNT_STRIDE] @0 | int lists[16][ntok] @2048
//
// R12 = R8 verbatim (best measured: 100.5 us). A/B ledger:
//   R8  (this config)                          100.5
//   R9  (+MBD48/bounds3 +ws-frags +packed)     106.1
//   R11 (+ws-frags +packed only)               104.8  -> ws-frags cost +4.3
// Weights are read DIRECTLY from W1/W2 (L2-hot: all 512 blocks share the
// same 256 KB; scattered dwords are throughput-cheap from L2). Do NOT move
// them into ws — the harness's 262 MB 0xAA fill right before the timed
// launch leaves ws L2-cold (R11 regression).
//
// Domain-major + MFMA. prep: jobA out=h stream; jobB membership detect +
// per-domain position compaction. mlp5: W1/W2 held in MFMA B-FRAGMENTS
// (bf16, 32 VGPRs) loaded ONCE per wave -> zero per-iteration weight reads.
// Per 16-token group: step1 U=HxW1 (4 mfma), gelu on D-frags, repack D->A
// via padded LDS, step2 C=UxW2 (4 mfma), atomicAdd 0.1*corr into out.
// Layouts (16x16x32 bf16, HW-verified): A[m=lane&15][k=quad*8+j];
// C/D col=lane&15,row=quad*4+reg; B[k=quad*8+j][n=lane&15].

typedef __attribute__((ext_vector_type(8))) short bf16x8;
typedef __attribute__((ext_vector_type(4))) float f32x4;

__device__ __forceinline__ short f2bf(float f) {   // fp32 -> bf16 bits, RNE
    unsigned u = __float_as_uint(f);
    u += 0x7FFFu + ((u >> 16) & 1u);
    return (short)(u >> 16);
}

// ---------------------------------------------------------------------------
__global__ void prep_kernel(const int* __restrict__ x,
                            const float* __restrict__ tab,
                            const unsigned char* __restrict__ memb,
                            float* __restrict__ out,
                            int* __restrict__ cnt,      // [16*CNT_STRIDE]
                            int* __restrict__ lists,    // [16][ntok]
                            int ntok)
{
    const int thr = threadIdx.x;
    const int bid = blockIdx.x;
    if (bid < NBA) {
        // ---- job A: out = embed_table[x]  (coalesced float4 gather-stream)
        const int nf4 = ntok * 16;
        for (int i = bid * NTHREADS + thr; i < nf4; i += NBA * NTHREADS) {
            int t = i >> 4, s = i & 15;
            int tok = x[t];
            float4 hv = ((const float4*)(tab + (size_t)tok * EDIM))[s];
            ((float4*)(out + (size_t)t * EDIM))[s] = hv;
        }
        return;
    }
    // ---- job B: membership dtype detect + per-domain compaction
    __shared__ int det;
    __shared__ int lcnt[DDOM], lbase[DDOM], lpos[DDOM];
    if (thr == 0) det = 0;
    if (thr < DDOM) lcnt[thr] = 0;
    __syncthreads();
    {   // scan first 4096 bytes (membership >= 804112 elements >= 1 B: in-bounds)
        const uint4 v = ((const uint4*)memb)[thr];
        unsigned int w[4] = {v.x, v.y, v.z, v.w};
        int saw = 0;
        #pragma unroll
        for (int dw = 0; dw < 4; ++dw)
            #pragma unroll
            for (int b = 0; b < 4; ++b) {
                unsigned int byte = (w[dw] >> (8 * b)) & 0xFFu;
                if (byte > 1u) saw |= 1;            // bf16 signature bytes
                if (byte == 1u && b != 0) saw |= 2; // '1' at offset %4 != 0 -> u8
            }
        if (saw) atomicOr(&det, saw);
    }
    __syncthreads();
    const int mcode = det;

    const int t = (bid - NBA) * NTHREADS + thr;
    unsigned int m = 0;
    if (t < ntok) {
        int tok = x[t];
        if (mcode & 1) {          // bf16 0.0/1.0
            const unsigned short* p = (const unsigned short*)memb + (size_t)tok * DDOM;
            #pragma unroll
            for (int d = 0; d < DDOM; ++d) m |= (unsigned)(p[d] != 0) << d;
        } else if (mcode & 2) {   // uint8
            const unsigned char* p = memb + (size_t)tok * DDOM;
            #pragma unroll
            for (int d = 0; d < DDOM; ++d) m |= (unsigned)(p[d] != 0) << d;
        } else {                  // int32
            const int* p = (const int*)memb + (size_t)tok * DDOM;
            #pragma unroll
            for (int d = 0; d < DDOM; ++d) m |= (unsigned)(p[d] != 0) << d;
        }
    }
    #pragma unroll
    for (int d = 0; d < DDOM; ++d)
        if ((m >> d) & 1u) atomicAdd(&lcnt[d], 1);
    __syncthreads();
    if (thr < DDOM) {
        lbase[thr] = atomicAdd(&cnt[thr * CNT_STRIDE], lcnt[thr]);  // padded target
        lpos[thr] = 0;
    }
    __syncthreads();
    #pragma unroll
    for (int d = 0; d < DDOM; ++d)
        if ((m >> d) & 1u) {
            int p = atomicAdd(&lpos[d], 1);
            lists[(size_t)d * ntok + lbase[d] + p] = t;   // position
        }
}

// ---------------------------------------------------------------------------
// mlp5: grid = 16 domains x 32 blocks, 256 threads (4 waves), 2 blocks/CU.
// Wave processes 16-token groups; weights live in bf16 MFMA fragments.
// ---------------------------------------------------------------------------
__global__ __launch_bounds__(256, 2) void mlp5_kernel(
    const int* __restrict__ lists,
    const int* __restrict__ cnt,
    const int* __restrict__ x,
    const float* __restrict__ tab,
    const float* __restrict__ W1,   // [D][E][DK]
    const float* __restrict__ W2,   // [D][DK][E]
    float* __restrict__ out,
    int ntok)
{
    __shared__ float u_lds[4][16][36];   // per-wave U repack, 36-stride (pad) 9.2 KB

    const int thr = threadIdx.x, lane = thr & 63, wid = thr >> 6;
    const int d    = blockIdx.x >> 5;
    const int blk  = blockIdx.x & (MBD - 1);
    const int n    = cnt[d * CNT_STRIDE];
    if (n == 0) return;

    const int col  = lane & 15;   // n-index inside a 16-wide tile
    const int quad = lane >> 4;   // k-index base = quad*8

    // ---- weight fragments, once per wave. B[k=quad*8+j][n=col] ----
    const float* __restrict__ w1g = W1 + d * (EDIM * DKDIM);  // [e][ko]
    const float* __restrict__ w2g = W2 + d * (DKDIM * EDIM);  // [k][e]
    bf16x8 w1f[2][2];   // [K-tile tk: e=tk*32+quad*8+j][n-half tn: ko=tn*16+col]
    #pragma unroll
    for (int tk = 0; tk < 2; ++tk)
        #pragma unroll
        for (int tn = 0; tn < 2; ++tn)
            #pragma unroll
            for (int j = 0; j < 8; ++j)
                w1f[tk][tn][j] = f2bf(w1g[(tk * 32 + quad * 8 + j) * DKDIM + tn * 16 + col]);
    bf16x8 w2f[4];      // [e-tile te: k=quad*8+j, n=e=te*16+col]
    #pragma unroll
    for (int te = 0; te < 4; ++te)
        #pragma unroll
        for (int j = 0; j < 8; ++j)
            w2f[te][j] = f2bf(w2g[(quad * 8 + j) * EDIM + te * 16 + col]);

    const int ngrp = (n + 15) >> 4;
    for (int g = blk * 4 + wid; g < ngrp; g += MBD * 4) {
        const int base = g * 16;
        // lane carries token row m=col of this group
        const int ti = base + col;
        const bool v = ti < n;
        const int pos   = v ? lists[(size_t)d * ntok + ti] : 0;
        const int tokid = v ? x[pos] : 0;

        // A-fragments of h: A[m=col][k=e=tk*32+quad*8+j]
        const float* __restrict__ hrow = tab + (size_t)tokid * EDIM;
        bf16x8 ha[2];
        #pragma unroll
        for (int tk = 0; tk < 2; ++tk) {
            f32x4 a = *(const f32x4*)(hrow + tk * 32 + quad * 8);
            f32x4 b = *(const f32x4*)(hrow + tk * 32 + quad * 8 + 4);
            ha[tk][0] = f2bf(a.x); ha[tk][1] = f2bf(a.y);
            ha[tk][2] = f2bf(a.z); ha[tk][3] = f2bf(a.w);
            ha[tk][4] = f2bf(b.x); ha[tk][5] = f2bf(b.y);
            ha[tk][6] = f2bf(b.z); ha[tk][7] = f2bf(b.w);
        }

        // ---- step1: U[16 tok x 32 ko], 2 n-halves x K=64 (2 mfma each) ----
        #pragma unroll
        for (int tn = 0; tn < 2; ++tn) {
            f32x4 acc = {0.f, 0.f, 0.f, 0.f};
            acc = __builtin_amdgcn_mfma_f32_16x16x32_bf16(ha[0], w1f[0][tn], acc, 0, 0, 0);
            acc = __builtin_amdgcn_mfma_f32_16x16x32_bf16(ha[1], w1f[1][tn], acc, 0, 0, 0);
            // gelu on D-frag (D[m=quad*4+r][ko=tn*16+col]) -> u_lds[m][ko]
            #pragma unroll
            for (int r = 0; r < 4; ++r) {
                float u = acc[r];
                float gg, au = fabsf(u);
                if (__builtin_expect(au > 0.35f, 0)) {
                    gg = 0.5f * u * (1.f + erff(u * 0.70710678118654752f));
                } else {
                    float uu = u * u;
                    gg = u * (0.5f + u * (0.3989422804f + uu * (-0.06649038f + uu * 0.00997356f)));
                }
                u_lds[wid][quad * 4 + r][tn * 16 + col] = gg;
            }
        }

        // ---- repack U: D-layout -> A-layout (same-wave RAW via in-order DS) ----
        bf16x8 ua;
        {
            const float* __restrict__ up = &u_lds[wid][col][quad * 8];
            f32x4 a = *(const f32x4*)(up);
            f32x4 b = *(const f32x4*)(up + 4);
            ua[0] = f2bf(a.x); ua[1] = f2bf(a.y); ua[2] = f2bf(a.z); ua[3] = f2bf(a.w);
            ua[4] = f2bf(b.x); ua[5] = f2bf(b.y); ua[6] = f2bf(b.z); ua[7] = f2bf(b.w);
        }

        // ---- step2: C[16 tok x 64 e] = U x W2; atomicAdd 0.1*corr ----
        #pragma unroll
        for (int te = 0; te < 4; ++te) {
            f32x4 acc = {0.f, 0.f, 0.f, 0.f};
            acc = __builtin_amdgcn_mfma_f32_16x16x32_bf16(ua, w2f[te], acc, 0, 0, 0);
            #pragma unroll
            for (int r = 0; r < 4; ++r) {
                int m  = quad * 4 + r;
                int pm = __shfl(pos, m, 64);      // pos of token row m
                if (base + m < n) {
                    atomicAdd(&out[(size_t)pm * EDIM + te * 16 + col], 0.1f * acc[r]);
                }
            }
        }
    }
}

// ---------------------------------------------------------------------------
// Fallback (ws too small): round-2 fused kernel, known-correct.
// ---------------------------------------------------------------------------
__global__ __launch_bounds__(256, 4) void domain_embed_fused(
    const int* __restrict__ x, const float* __restrict__ tab,
    const float* __restrict__ W1, const float* __restrict__ W2,
    const unsigned char* __restrict__ memb, float* __restrict__ out, int ntok)
{
    __shared__ float h_lds[32][EDIM];
    __shared__ float corr[32][EDIM];
    __shared__ int   tok_lds[32];
    __shared__ unsigned int mask_lds[32];
    __shared__ unsigned short pairs[32 * DDOM];
    __shared__ int npairs;
    __shared__ int det_wave[4];
    const int thr = threadIdx.x, lane = thr & 63, wid = thr >> 6;
    const int tok0 = blockIdx.x * 32;
    if (thr < 32) { int t = tok0 + thr; tok_lds[thr] = (t < ntok) ? x[t] : 0; }
    #pragma unroll
    for (int i = 0; i < 8; ++i) ((float*)corr)[thr + i * 256] = 0.f;
    if (thr == 0) npairs = 0;
    {
        const uint4 v = ((const uint4*)memb)[thr];
        unsigned int w[4] = {v.x, v.y, v.z, v.w};
        bool sawbf = false, saw8 = false;
        #pragma unroll
        for (int dw = 0; dw < 4; ++dw)
            #pragma unroll
            for (int b = 0; b < 4; ++b) {
                unsigned int byte = (w[dw] >> (8 * b)) & 0xFFu;
                if (byte > 1u) sawbf = true;
                if (byte == 1u && b != 0) saw8 = true;
            }
        unsigned long long b1 = __ballot(sawbf), b2 = __ballot(saw8);
        if (lane == 0) det_wave[wid] = (b1 ? 1 : 0) | (b2 ? 2 : 0);
    }
    __syncthreads();
    const int mcode = det_wave[0] | det_wave[1] | det_wave[2] | det_wave[3];
    #pragma unroll
    for (int pass = 0; pass < 2; ++pass) {
        int row = pass * 16 + (thr >> 4);
        const float4 hv = ((const float4*)(tab + (size_t)tok_lds[row] * EDIM))[thr & 15];
        ((float4*)&h_lds[row][0])[thr & 15] = hv;
    }
    if (thr < 32) {
        int tokid = tok_lds[thr];
        unsigned int m = 0;
        if (mcode & 1) { const unsigned short* p = (const unsigned short*)memb + (size_t)tokid * DDOM;
            #pragma unroll
            for (int d = 0; d < DDOM; ++d) m |= (unsigned)(p[d] != 0) << d;
        } else if (mcode & 2) { const unsigned char* p = memb + (size_t)tokid * DDOM;
            #pragma unroll
            for (int d = 0; d < DDOM; ++d) m |= (unsigned)(p[d] != 0) << d;
        } else { const int* p = (const int*)memb + (size_t)tokid * DDOM;
            #pragma unroll
            for (int d = 0; d < DDOM; ++d) m |= (unsigned)(p[d] != 0) << d;
        }
        mask_lds[thr] = m;
    }
    __syncthreads();
    for (int cc = thr; cc < 32 * DDOM; cc += 256) {
        int t = cc >> 4, d = cc & 15;
        if ((mask_lds[t] >> d) & 1u) { int idx = atomicAdd(&npairs, 1); pairs[idx] = (unsigned short)cc; }
    }
    __syncthreads();
    const int np = npairs, k = lane & 31, p = lane >> 5;
    for (int pi = wid; pi < np; pi += 4) {
        int cc = pairs[pi], t = cc >> 4, d = cc & 15;
        const float* __restrict__ w1 = W1 + d * (EDIM * DKDIM);
        float u = 0.f;
        #pragma unroll
        for (int j4 = 0; j4 < 8; ++j4) {
            float4 hv = ((const float4*)&h_lds[t][p * 32])[j4];
            int e = p * 32 + j4 * 4;
            u = fmaf(hv.x, w1[(e + 0) * DKDIM + k], u);
            u = fmaf(hv.y, w1[(e + 1) * DKDIM + k], u);
            u = fmaf(hv.z, w1[(e + 2) * DKDIM + k], u);
            u = fmaf(hv.w, w1[(e + 3) * DKDIM + k], u);
        }
        u += __shfl_xor(u, 32, 64);
        float gg, au = fabsf(u);
        if (__builtin_expect(__ballot(au > 0.35f) != 0ull, 0))
            gg = 0.5f * u * (1.f + erff(u * 0.70710678118654752f));
        else { float uu = u * u; gg = u * (0.5f + u * (0.3989422804f + uu * (-0.06649038f + uu * 0.00997356f))); }
        const float* __restrict__ w2 = W2 + d * (DKDIM * EDIM);
        float cp = 0.f;
        #pragma unroll
        for (int kk = 0; kk < DKDIM; ++kk) cp = fmaf(__shfl(gg, kk, 64), w2[kk * EDIM + lane], cp);
        atomicAdd(&corr[t][lane], cp);
    }
    __syncthreads();
    #pragma unroll
    for (int pass = 0; pass < 2; ++pass) {
        int row = pass * 16 + (thr >> 4), gt = tok0 + row;
        if (gt < ntok) {
            float4 hv = ((const float4*)&h_lds[row][0])[thr & 15];
            float4 cv = ((const float4*)&corr[row][0])[thr & 15];
            float4 o = {hv.x + 0.1f * cv.x, hv.y + 0.1f * cv.y, hv.z + 0.1f * cv.z, hv.w + 0.1f * cv.w};
            ((float4*)(out + (size_t)gt * EDIM))[thr & 15] = o;
        }
    }
}

extern "C" void kernel_launch(void* const* d_in, const int* in_sizes, int n_in,
                              void* d_out, int out_size, void* d_ws, size_t ws_size,
                              hipStream_t stream) {
    const int*   x    = (const int*)  d_in[0];
    const float* tab  = (const float*)d_in[1];
    const float* W1   = (const float*)d_in[2];
    const float* W2   = (const float*)d_in[3];
    const unsigned char* memb = (const unsigned char*)d_in[4];
    float* out = (float*)d_out;
    const int ntok = in_sizes[0];

    // ws: cnt[16*CNT_STRIDE] @0 (2048 B) | lists @2048
    const size_t lists_off = (size_t)DDOM * CNT_STRIDE * sizeof(int);
    const size_t need      = lists_off + (size_t)DDOM * (size_t)ntok * sizeof(int);
    if (ws_size >= need) {
        int* cnt   = (int*)d_ws;
        int* lists = (int*)((char*)d_ws + lists_off);
        hipMemsetAsync(d_ws, 0, lists_off, stream);        // zero cnt (ws poisoned 0xAA)
        const int nbb = (ntok + NTHREADS - 1) / NTHREADS;
        prep_kernel<<<NBA + nbb, NTHREADS, 0, stream>>>(
            x, tab, memb, out, cnt, lists, ntok);
        mlp5_kernel<<<DDOM * MBD, NTHREADS, 0, stream>>>(
            lists, cnt, x, tab, W1, W2, out, ntok);
    } else {
        const int blocks = (ntok + 31) / 32;
        domain_embed_fused<<<blocks, NTHREADS, 0, stream>>>(x, tab, W1, W2, memb, out, ntok);
    }
}